// Round 2
// baseline (374.215 us; speedup 1.0000x reference)
//
#include <hip/hip_runtime.h>
#include <hip/hip_bf16.h>
#include <stdint.h>

namespace {

constexpr int B = 8, T = 200, U = 50, D = 512, INNER = 640, VOCAB = 1024;
constexpr int M_TOTAL = B * T * U;          // 80000
constexpr int ROWS_E = B * T;               // 1600
constexpr int ROWS_D = B * U;               // 400
constexpr int ROWS_ED = ROWS_E + ROWS_D;    // 2000
constexpr int BM = 64;                      // rows per block (80000/64 = 1250)
constexpr int KSTEPS = INNER / 32;          // 20

typedef __bf16 bf16x8 __attribute__((ext_vector_type(8)));
typedef float  f32x4  __attribute__((ext_vector_type(4)));
typedef unsigned short u16;

__device__ __forceinline__ u16 f2bf(float f) {
  uint32_t u = __float_as_uint(f);
  uint32_t rounding = 0x7FFFu + ((u >> 16) & 1u);   // round-to-nearest-even
  return (u16)((u + rounding) >> 16);
}

__device__ __forceinline__ float fast_tanh(float x) {
  float e = __expf(2.0f * x);
  float r = __builtin_amdgcn_rcpf(e + 1.0f);
  return 1.0f - 2.0f * r;
}

// ---------------------------------------------------------------------------
// Kernel 1: ED[0:1600]  = enc @ W1 + b1   (fp32)
//           ED[1600:2000] = dec @ W1      (fp32)
// ---------------------------------------------------------------------------
__global__ __launch_bounds__(320) void k_ed(const float* __restrict__ enc,
                                            const float* __restrict__ dec,
                                            const float* __restrict__ W1,
                                            const float* __restrict__ b1,
                                            float* __restrict__ ED) {
  __shared__ float rows[8 * D];   // 16 KiB
  const int r0 = blockIdx.x * 8;
  const bool is_enc = (r0 < ROWS_E);
  const float* src = is_enc ? (enc + (size_t)r0 * D)
                            : (dec + (size_t)(r0 - ROWS_E) * D);
  for (int i = threadIdx.x; i < 8 * D; i += 320) rows[i] = src[i];
  __syncthreads();

  const int c0 = threadIdx.x, c1 = threadIdx.x + 320;
  float acc[8][2];
  const float bias0 = is_enc ? b1[c0] : 0.f;
  const float bias1 = is_enc ? b1[c1] : 0.f;
#pragma unroll
  for (int r = 0; r < 8; ++r) { acc[r][0] = bias0; acc[r][1] = bias1; }

  for (int d = 0; d < D; d += 4) {
    float4 rv[8];
#pragma unroll
    for (int r = 0; r < 8; ++r)
      rv[r] = *reinterpret_cast<const float4*>(&rows[r * D + d]);
#pragma unroll
    for (int dd = 0; dd < 4; ++dd) {
      const float w0 = W1[(size_t)(d + dd) * INNER + c0];
      const float w1 = W1[(size_t)(d + dd) * INNER + c1];
#pragma unroll
      for (int r = 0; r < 8; ++r) {
        const float x = (dd == 0) ? rv[r].x : (dd == 1) ? rv[r].y
                        : (dd == 2) ? rv[r].z : rv[r].w;
        acc[r][0] = fmaf(x, w0, acc[r][0]);
        acc[r][1] = fmaf(x, w1, acc[r][1]);
      }
    }
  }
#pragma unroll
  for (int r = 0; r < 8; ++r) {
    ED[(size_t)(r0 + r) * INNER + c0] = acc[r][0];
    ED[(size_t)(r0 + r) * INNER + c1] = acc[r][1];
  }
}

// ---------------------------------------------------------------------------
// Kernel 2: pack W2 (fp32, [INNER][VOCAB]) into bf16 MFMA B-fragment order.
// Fragment f = ks*64 + nf  (ks: K-step of 32, nf: 16-col group).
// Within a fragment, lane l holds 8 bf16: n = nf*16 + (l&15),
// k = ks*32 + (l>>4)*8 + j  -> each fragment is a contiguous 1 KiB block,
// so k_main's B loads are perfectly coalesced dwordx4 streams.
// ---------------------------------------------------------------------------
__global__ __launch_bounds__(256) void k_w2b(const float* __restrict__ W2,
                                             u16* __restrict__ W2B) {
  const int idx = blockIdx.x * 256 + threadIdx.x;   // < 81920
  const int lane = idx & 63;
  const int f = idx >> 6;
  const int ks = f >> 6;
  const int nf = f & 63;
  const int n = nf * 16 + (lane & 15);
  const int k = ks * 32 + (lane >> 4) * 8;
  u16 v[8];
#pragma unroll
  for (int j = 0; j < 8; ++j)
    v[j] = f2bf(W2[(size_t)(k + j) * VOCAB + n]);
  uint64_t lo = (uint64_t)v[0] | ((uint64_t)v[1] << 16) |
                ((uint64_t)v[2] << 32) | ((uint64_t)v[3] << 48);
  uint64_t hi = (uint64_t)v[4] | ((uint64_t)v[5] << 16) |
                ((uint64_t)v[6] << 32) | ((uint64_t)v[7] << 48);
  uint64_t* dst = reinterpret_cast<uint64_t*>(W2B + (size_t)idx * 8);
  dst[0] = lo;
  dst[1] = hi;
}

// ---------------------------------------------------------------------------
// Kernel 3: out[m][n] = tanh(E1[t(m)] + D1[u(m)]) @ W2 + b2
// Block: 64 rows x 1024 cols, 512 threads (8 waves, each 64x128 slab).
// Phase 1: hidden 64x640 -> bf16 LDS (80 KiB, XOR-swizzled), ONE barrier.
// Phase 2: 20 K-steps of pure MFMA, zero barriers.
// ---------------------------------------------------------------------------
__global__ __launch_bounds__(512, 2) void k_main(const float* __restrict__ ED,
                                                 const u16* __restrict__ W2B,
                                                 const float* __restrict__ b2,
                                                 float* __restrict__ out) {
  __shared__ u16 hid[BM * INNER];   // 81920 B, swizzle: byte ^= (row&7)<<4
  char* hid_b = reinterpret_cast<char*>(hid);

  const int tid = threadIdx.x;
  const int m0 = blockIdx.x * BM;

  // ---- Phase 1: hidden tile ----
  {
    const int r  = tid >> 3;          // 0..63
    const int lw = tid & 7;           // 0..7
    const int m = m0 + r;
    const int b = m / (T * U);
    const int rem = m - b * (T * U);
    const int t = rem / U;
    const int u = rem - t * U;
    const float* Erow = ED + (size_t)(b * T + t) * INNER;
    const float* Drow = ED + (size_t)(ROWS_E + b * U + u) * INNER;
    const int rx = (r & 7) << 4;
    const int rbase = r * (INNER * 2);
#pragma unroll 4
    for (int i = 0; i < 20; ++i) {
      const int k = lw * 4 + i * 32;
      const float4 e  = *reinterpret_cast<const float4*>(Erow + k);
      const float4 dv = *reinterpret_cast<const float4*>(Drow + k);
      const u16 h0 = f2bf(fast_tanh(e.x + dv.x));
      const u16 h1 = f2bf(fast_tanh(e.y + dv.y));
      const u16 h2 = f2bf(fast_tanh(e.z + dv.z));
      const u16 h3 = f2bf(fast_tanh(e.w + dv.w));
      const uint64_t pack = (uint64_t)h0 | ((uint64_t)h1 << 16) |
                            ((uint64_t)h2 << 32) | ((uint64_t)h3 << 48);
      const int byte = (rbase + k * 2) ^ rx;
      *reinterpret_cast<uint64_t*>(hid_b + byte) = pack;
    }
  }
  __syncthreads();   // the only barrier

  // ---- Phase 2: MFMA ----
  const int w    = tid >> 6;     // 0..7, owns cols [w*128, w*128+128)
  const int lane = tid & 63;
  const int llo  = lane & 15;
  const int lhi  = lane >> 4;

  f32x4 acc[4][8];
#pragma unroll
  for (int mi = 0; mi < 4; ++mi)
#pragma unroll
    for (int ni = 0; ni < 8; ++ni) acc[mi][ni] = (f32x4){0.f, 0.f, 0.f, 0.f};

  // Per-lane A byte offsets (row = mi*16+llo) and B base
  const u16* Bptr = W2B + ((size_t)(w * 8) * 64 + lane) * 8;

#pragma unroll 2
  for (int ks = 0; ks < KSTEPS; ++ks) {
    bf16x8 a[4];
#pragma unroll
    for (int mi = 0; mi < 4; ++mi) {
      const int row = mi * 16 + llo;
      const int byte = (row * (INNER * 2) + ks * 64 + lhi * 16) ^ ((row & 7) << 4);
      a[mi] = *reinterpret_cast<const bf16x8*>(hid_b + byte);
    }
    bf16x8 bfr[8];
#pragma unroll
    for (int ni = 0; ni < 8; ++ni) {
      bfr[ni] = *reinterpret_cast<const bf16x8*>(Bptr + ((size_t)(ks * 64 + ni) * 64) * 8);
    }
#pragma unroll
    for (int ni = 0; ni < 8; ++ni)
#pragma unroll
      for (int mi = 0; mi < 4; ++mi)
        acc[mi][ni] = __builtin_amdgcn_mfma_f32_16x16x32_bf16(a[mi], bfr[ni], acc[mi][ni], 0, 0, 0);
  }

  // ---- Epilogue ----
  float b2v[8];
#pragma unroll
  for (int ni = 0; ni < 8; ++ni) b2v[ni] = b2[w * 128 + ni * 16 + llo];

#pragma unroll
  for (int mi = 0; mi < 4; ++mi) {
#pragma unroll
    for (int q = 0; q < 4; ++q) {
      const int row = m0 + mi * 16 + lhi * 4 + q;
      float* orow = out + (size_t)row * VOCAB + w * 128 + llo;
#pragma unroll
      for (int ni = 0; ni < 8; ++ni) {
        orow[ni * 16] = acc[mi][ni][q] + b2v[ni];
      }
    }
  }
}

}  // namespace

extern "C" void kernel_launch(void* const* d_in, const int* in_sizes, int n_in,
                              void* d_out, int out_size, void* d_ws, size_t ws_size,
                              hipStream_t stream) {
  const float* enc = (const float*)d_in[0];
  const float* dec = (const float*)d_in[1];
  const float* W1  = (const float*)d_in[2];
  const float* b1  = (const float*)d_in[3];
  const float* W2  = (const float*)d_in[4];
  const float* b2  = (const float*)d_in[5];
  float* out = (float*)d_out;

  float* ED  = (float*)d_ws;                                        // 2000*640*4 = 5,120,000 B
  u16*   W2B = (u16*)((char*)d_ws + (size_t)ROWS_ED * INNER * 4);   // 1024*640*2 = 1,310,720 B

  hipLaunchKernelGGL(k_ed, dim3(ROWS_ED / 8), dim3(320), 0, stream,
                     enc, dec, W1, b1, ED);
  hipLaunchKernelGGL(k_w2b, dim3((KSTEPS * 64 * 64) / 256), dim3(256), 0, stream,
                     W2, W2B);
  hipLaunchKernelGGL(k_main, dim3(M_TOTAL / BM), dim3(512), 0, stream,
                     ED, W2B, b2, out);
}

// Round 3
// 292.900 us; speedup vs baseline: 1.2776x; 1.2776x over previous
//
#include <hip/hip_runtime.h>
#include <hip/hip_bf16.h>
#include <stdint.h>

namespace {

constexpr int B = 8, T = 200, U = 50, D = 512, INNER = 640, VOCAB = 1024;
constexpr int M_TOTAL = B * T * U;          // 80000
constexpr int ROWS_E = B * T;               // 1600
constexpr int ROWS_D = B * U;               // 400
constexpr int ROWS_ED = ROWS_E + ROWS_D;    // 2000
constexpr int BM = 128, BN = 256, BK = 64;
constexpr int NSTEP = INNER / BK;           // 10

typedef __bf16 bf16x8 __attribute__((ext_vector_type(8)));
typedef float  f32x4  __attribute__((ext_vector_type(4)));
typedef unsigned short u16;
typedef unsigned int   u32;

__device__ __forceinline__ u16 f2bf(float f) {
  uint32_t u = __float_as_uint(f);
  uint32_t rounding = 0x7FFFu + ((u >> 16) & 1u);   // RNE
  return (u16)((u + rounding) >> 16);
}

__device__ __forceinline__ float fast_tanh(float x) {
  float e = __expf(2.0f * x);
  float r = __builtin_amdgcn_rcpf(e + 1.0f);
  return 1.0f - 2.0f * r;
}

#define GLD16(gp, lp) __builtin_amdgcn_global_load_lds( \
    (const __attribute__((address_space(1))) u32*)(gp), \
    (__attribute__((address_space(3))) u32*)(lp), 16, 0, 0)

// ---------------------------------------------------------------------------
// Kernel 1: ED[0:1600] = enc @ W1 + b1 ; ED[1600:2000] = dec @ W1   (fp32)
// 16 rows/block -> 125 blocks; W1 re-read traffic = 125 x 1.25 MB = 156 MB
// ---------------------------------------------------------------------------
__global__ __launch_bounds__(320) void k_ed(const float* __restrict__ enc,
                                            const float* __restrict__ dec,
                                            const float* __restrict__ W1,
                                            const float* __restrict__ b1,
                                            float* __restrict__ ED) {
  __shared__ float rows[16 * D];   // 32 KiB
  const int r0 = blockIdx.x * 16;
  const bool is_enc = (r0 < ROWS_E);            // blocks 0..99 enc, 100..124 dec
  const float* src = is_enc ? (enc + (size_t)r0 * D)
                            : (dec + (size_t)(r0 - ROWS_E) * D);
  for (int i = threadIdx.x; i < 16 * D; i += 320) rows[i] = src[i];
  __syncthreads();

  const int c0 = threadIdx.x, c1 = threadIdx.x + 320;
  float acc[16][2];
  const float bias0 = is_enc ? b1[c0] : 0.f;
  const float bias1 = is_enc ? b1[c1] : 0.f;
#pragma unroll
  for (int r = 0; r < 16; ++r) { acc[r][0] = bias0; acc[r][1] = bias1; }

  for (int d = 0; d < D; d += 4) {
    float4 rv[16];
#pragma unroll
    for (int r = 0; r < 16; ++r)
      rv[r] = *reinterpret_cast<const float4*>(&rows[r * D + d]);
#pragma unroll
    for (int dd = 0; dd < 4; ++dd) {
      const float w0 = W1[(size_t)(d + dd) * INNER + c0];
      const float w1 = W1[(size_t)(d + dd) * INNER + c1];
#pragma unroll
      for (int r = 0; r < 16; ++r) {
        const float x = (dd == 0) ? rv[r].x : (dd == 1) ? rv[r].y
                        : (dd == 2) ? rv[r].z : rv[r].w;
        acc[r][0] = fmaf(x, w0, acc[r][0]);
        acc[r][1] = fmaf(x, w1, acc[r][1]);
      }
    }
  }
#pragma unroll
  for (int r = 0; r < 16; ++r) {
    ED[(size_t)(r0 + r) * INNER + c0] = acc[r][0];
    ED[(size_t)(r0 + r) * INNER + c1] = acc[r][1];
  }
}

// ---------------------------------------------------------------------------
// Kernel 2: pack W2 -> bf16 MFMA B-fragment order.
// Fragment f = ks*64 + nf (ks: K/32 step, nf: 16-col group); 1 KiB each:
// lane l holds 8 bf16 {n = nf*16 + (l&15), k = ks*32 + (l>>4)*8 + j}.
// ---------------------------------------------------------------------------
__global__ __launch_bounds__(256) void k_w2b(const float* __restrict__ W2,
                                             u16* __restrict__ W2B) {
  const int idx = blockIdx.x * 256 + threadIdx.x;   // < 81920
  const int lane = idx & 63;
  const int f = idx >> 6;
  const int ks = f >> 6;
  const int nf = f & 63;
  const int n = nf * 16 + (lane & 15);
  const int k = ks * 32 + (lane >> 4) * 8;
  u16 v[8];
#pragma unroll
  for (int j = 0; j < 8; ++j)
    v[j] = f2bf(W2[(size_t)(k + j) * VOCAB + n]);
  uint64_t lo = (uint64_t)v[0] | ((uint64_t)v[1] << 16) |
                ((uint64_t)v[2] << 32) | ((uint64_t)v[3] << 48);
  uint64_t hi = (uint64_t)v[4] | ((uint64_t)v[5] << 16) |
                ((uint64_t)v[6] << 32) | ((uint64_t)v[7] << 48);
  uint64_t* dst = reinterpret_cast<uint64_t*>(W2B + (size_t)idx * 8);
  dst[0] = lo;
  dst[1] = hi;
}

// ---------------------------------------------------------------------------
// Kernel 3: out = tanh(E1+D1) @ W2 + b2 — m97-style 2-barrier K-loop.
// BM=128 x BN=256, BK=64, 512 thr (8 waves 2x4), grid (625,4).
// B: global_load_lds x16B from fragment-packed W2B -> linear LDS (0 conflicts)
// A: computed (tanh) into XOR-swizzled LDS.
// ---------------------------------------------------------------------------
__global__ __launch_bounds__(512) void k_main(const float* __restrict__ ED,
                                              const u16* __restrict__ W2B,
                                              const float* __restrict__ b2,
                                              float* __restrict__ out) {
  __shared__ u16 At[BM * BK];   // 16 KiB, byte ^= (row&7)<<4
  __shared__ u16 Bt[BN * BK];   // 32 KiB, 32 fragments x 1 KiB, linear

  const int tid = threadIdx.x;
  const int m0 = blockIdx.x * BM;
  const int nf0 = blockIdx.y * (BN / 16);   // global 16-col-group base

  // per-thread A-compute assignment: row = tid>>2 (0..127), 16 k's
  const int ar  = tid >> 2;
  const int ak0 = (tid & 3) * 16;
  {
  }
  const int m = m0 + ar;
  const int bb = m / (T * U);
  const int rem = m - bb * (T * U);
  const int tt = rem / U;
  const int uu = rem - tt * U;
  const float* Erow = ED + (size_t)(bb * T + tt) * INNER;
  const float* Drow = ED + (size_t)(ROWS_E + bb * U + uu) * INNER;
  const int arx   = (ar & 7) << 4;
  const int abase = ar * (BK * 2);

  const int lane = tid & 63;
  const int wid  = tid >> 6;
  const int wr = wid >> 2, wc = wid & 3;
  const int llo = lane & 15, lhi = lane >> 4;

  char* At_b = reinterpret_cast<char*>(At);
  char* Bt_b = reinterpret_cast<char*>(Bt);
  const char* W2Bb = reinterpret_cast<const char*>(W2B);

  f32x4 acc[4][4];
#pragma unroll
  for (int i = 0; i < 4; ++i)
#pragma unroll
    for (int j = 0; j < 4; ++j) acc[i][j] = (f32x4){0.f, 0.f, 0.f, 0.f};

  for (int s = 0; s < NSTEP; ++s) {
    const int kc = s * BK;

    // ---- stage B (async DMA): 32 KiB = two 16 KiB chunks (ks=2s, 2s+1) ----
    {
      const size_t G0 = (size_t)(2 * s * 64 + nf0) * 1024;
      const u32 lds_u = wid * 1024 + lane * 16;   // == tid*16
#pragma unroll
      for (int c = 0; c < 4; ++c) {
        const size_t gb = G0 + (c < 2 ? 0 : 49152) + (size_t)c * 8192 + lds_u;
        GLD16(W2Bb + gb, Bt_b + c * 8192 + wid * 1024);
      }
    }

    // ---- compute A sub-tile: 128 rows x 64 k, bf16, swizzled ----
#pragma unroll
    for (int g = 0; g < 2; ++g) {
      const int k = ak0 + g * 8;
      const float4 e0 = *reinterpret_cast<const float4*>(Erow + kc + k);
      const float4 e1 = *reinterpret_cast<const float4*>(Erow + kc + k + 4);
      const float4 d0 = *reinterpret_cast<const float4*>(Drow + kc + k);
      const float4 d1 = *reinterpret_cast<const float4*>(Drow + kc + k + 4);
      const u32 p0 = (u32)f2bf(fast_tanh(e0.x + d0.x)) |
                     ((u32)f2bf(fast_tanh(e0.y + d0.y)) << 16);
      const u32 p1 = (u32)f2bf(fast_tanh(e0.z + d0.z)) |
                     ((u32)f2bf(fast_tanh(e0.w + d0.w)) << 16);
      const u32 p2 = (u32)f2bf(fast_tanh(e1.x + d1.x)) |
                     ((u32)f2bf(fast_tanh(e1.y + d1.y)) << 16);
      const u32 p3 = (u32)f2bf(fast_tanh(e1.z + d1.z)) |
                     ((u32)f2bf(fast_tanh(e1.w + d1.w)) << 16);
      const int byte = (abase + k * 2) ^ arx;
      int4 pk; pk.x = (int)p0; pk.y = (int)p1; pk.z = (int)p2; pk.w = (int)p3;
      *reinterpret_cast<int4*>(At_b + byte) = pk;
    }

    __syncthreads();   // drains DMA (vmcnt) + ds_writes (lgkmcnt)

    // ---- MFMA: 2 x K=32, 16 MFMA each ----
#pragma unroll
    for (int ksl = 0; ksl < 2; ++ksl) {
      bf16x8 a[4], bfr[4];
#pragma unroll
      for (int mi = 0; mi < 4; ++mi) {
        const int row = wr * 64 + mi * 16 + llo;
        const int byte = (row * 128 + ksl * 64 + lhi * 16) ^ ((row & 7) << 4);
        a[mi] = *reinterpret_cast<const bf16x8*>(At_b + byte);
      }
#pragma unroll
      for (int ni = 0; ni < 4; ++ni) {
        const int byte = (ksl * 16 + wc * 4 + ni) * 1024 + lane * 16;
        bfr[ni] = *reinterpret_cast<const bf16x8*>(Bt_b + byte);
      }
#pragma unroll
      for (int mi = 0; mi < 4; ++mi)
#pragma unroll
        for (int ni = 0; ni < 4; ++ni)
          acc[mi][ni] = __builtin_amdgcn_mfma_f32_16x16x32_bf16(a[mi], bfr[ni], acc[mi][ni], 0, 0, 0);
    }

    __syncthreads();   // protect tiles before next overwrite
  }

  // ---- epilogue ----
  const int n0 = nf0 * 16;
  float b2v[4];
#pragma unroll
  for (int ni = 0; ni < 4; ++ni) b2v[ni] = b2[n0 + wc * 64 + ni * 16 + llo];

#pragma unroll
  for (int mi = 0; mi < 4; ++mi) {
#pragma unroll
    for (int q = 0; q < 4; ++q) {
      const int row = m0 + wr * 64 + mi * 16 + lhi * 4 + q;
      float* orow = out + (size_t)row * VOCAB + n0 + wc * 64 + llo;
#pragma unroll
      for (int ni = 0; ni < 4; ++ni)
        orow[ni * 16] = acc[mi][ni][q] + b2v[ni];
    }
  }
}

}  // namespace

extern "C" void kernel_launch(void* const* d_in, const int* in_sizes, int n_in,
                              void* d_out, int out_size, void* d_ws, size_t ws_size,
                              hipStream_t stream) {
  const float* enc = (const float*)d_in[0];
  const float* dec = (const float*)d_in[1];
  const float* W1  = (const float*)d_in[2];
  const float* b1  = (const float*)d_in[3];
  const float* W2  = (const float*)d_in[4];
  const float* b2  = (const float*)d_in[5];
  float* out = (float*)d_out;

  float* ED  = (float*)d_ws;                                        // 5,120,000 B
  u16*   W2B = (u16*)((char*)d_ws + (size_t)ROWS_ED * INNER * 4);   // 1,310,720 B

  hipLaunchKernelGGL(k_ed, dim3(ROWS_ED / 16), dim3(320), 0, stream,
                     enc, dec, W1, b1, ED);
  hipLaunchKernelGGL(k_w2b, dim3((INNER / 32 * 64 * 64) / 256), dim3(256), 0, stream,
                     W2, W2B);
  hipLaunchKernelGGL(k_main, dim3(M_TOTAL / BM, VOCAB / BN), dim3(512), 0, stream,
                     ED, W2B, b2, out);
}

// Round 5
// 191.563 us; speedup vs baseline: 1.9535x; 1.5290x over previous
//
#include <hip/hip_runtime.h>
#include <hip/hip_bf16.h>
#include <stdint.h>

namespace {

constexpr int B = 8, T = 200, U = 50, D = 512, INNER = 640, VOCAB = 1024;
constexpr int M_TOTAL = B * T * U;          // 80000
constexpr int ROWS_E = B * T;               // 1600
constexpr int ROWS_D = B * U;               // 400
constexpr int ROWS_ED = ROWS_E + ROWS_D;    // 2000
constexpr int BM = 64;                      // rows per k_main block -> grid 1250
constexpr int KST = INNER / 32;             // 20 K-steps of 32

typedef __bf16 bf16x8 __attribute__((ext_vector_type(8)));
typedef float  f32x4  __attribute__((ext_vector_type(4)));
typedef unsigned short u16;
typedef unsigned int   u32;

__device__ __forceinline__ u16 f2bf(float f) {
  uint32_t u = __float_as_uint(f);
  uint32_t rounding = 0x7FFFu + ((u >> 16) & 1u);   // RNE
  return (u16)((u + rounding) >> 16);
}

__device__ __forceinline__ float fast_tanh(float x) {
  float e = __expf(2.0f * x);
  float r = __builtin_amdgcn_rcpf(e + 1.0f);
  return 1.0f - 2.0f * r;
}

// ---------------------------------------------------------------------------
// k_prep: merged GEMM1 (ED) + W2 fragment pack.
//   blocks [0,250):   ED[0:1600]=enc@W1+b1 ; ED[1600:2000]=dec@W1  (fp32)
//   blocks [250,506): W2B bf16 fragment pack (idx = (bx-250)*320+tid < 81920)
// ---------------------------------------------------------------------------
__global__ __launch_bounds__(320) void k_prep(const float* __restrict__ enc,
                                              const float* __restrict__ dec,
                                              const float* __restrict__ W1,
                                              const float* __restrict__ b1,
                                              const float* __restrict__ W2,
                                              float* __restrict__ ED,
                                              u16* __restrict__ W2B) {
  if (blockIdx.x >= 250) {
    // ---- W2 pack: fragment f = ks*64+nf (1 KiB each); lane l holds 8 bf16
    //      {n = nf*16 + (l&15), k = ks*32 + (l>>4)*8 + j} ----
    const int idx = (blockIdx.x - 250) * 320 + threadIdx.x;   // < 81920 exact
    const int lane = idx & 63;
    const int f = idx >> 6;
    const int ks = f >> 6;
    const int nf = f & 63;
    const int n = nf * 16 + (lane & 15);
    const int k = ks * 32 + (lane >> 4) * 8;
    u16 v[8];
#pragma unroll
    for (int j = 0; j < 8; ++j)
      v[j] = f2bf(W2[(size_t)(k + j) * VOCAB + n]);
    uint64_t lo = (uint64_t)v[0] | ((uint64_t)v[1] << 16) |
                  ((uint64_t)v[2] << 32) | ((uint64_t)v[3] << 48);
    uint64_t hi = (uint64_t)v[4] | ((uint64_t)v[5] << 16) |
                  ((uint64_t)v[6] << 32) | ((uint64_t)v[7] << 48);
    uint64_t* dst = reinterpret_cast<uint64_t*>(W2B + (size_t)idx * 8);
    dst[0] = lo;
    dst[1] = hi;
    return;
  }

  // ---- ED part ----
  __shared__ float rows[8 * D];   // 16 KiB
  const int r0 = blockIdx.x * 8;
  const bool is_enc = (r0 < ROWS_E);   // blocks 0..199 enc, 200..249 dec
  const float* src = is_enc ? (enc + (size_t)r0 * D)
                            : (dec + (size_t)(r0 - ROWS_E) * D);
  for (int i = threadIdx.x; i < 8 * D; i += 320) rows[i] = src[i];
  __syncthreads();

  const int c0 = threadIdx.x, c1 = threadIdx.x + 320;
  float acc[8][2];
  const float bias0 = is_enc ? b1[c0] : 0.f;
  const float bias1 = is_enc ? b1[c1] : 0.f;
#pragma unroll
  for (int r = 0; r < 8; ++r) { acc[r][0] = bias0; acc[r][1] = bias1; }

  for (int d = 0; d < D; d += 4) {
    float4 rv[8];
#pragma unroll
    for (int r = 0; r < 8; ++r)
      rv[r] = *reinterpret_cast<const float4*>(&rows[r * D + d]);
#pragma unroll
    for (int dd = 0; dd < 4; ++dd) {
      const float w0 = W1[(size_t)(d + dd) * INNER + c0];
      const float w1 = W1[(size_t)(d + dd) * INNER + c1];
#pragma unroll
      for (int r = 0; r < 8; ++r) {
        const float x = (dd == 0) ? rv[r].x : (dd == 1) ? rv[r].y
                        : (dd == 2) ? rv[r].z : rv[r].w;
        acc[r][0] = fmaf(x, w0, acc[r][0]);
        acc[r][1] = fmaf(x, w1, acc[r][1]);
      }
    }
  }
#pragma unroll
  for (int r = 0; r < 8; ++r) {
    ED[(size_t)(r0 + r) * INNER + c0] = acc[r][0];
    ED[(size_t)(r0 + r) * INNER + c1] = acc[r][1];
  }
}

// ---------------------------------------------------------------------------
// k_main: out[64 x 1024 tile] = tanh(E1+D1) @ W2 + b2
// 1024 thr = 16 waves, wave w owns cols [w*64, w*64+64) -> NO B duplication.
// Phase 1: A = 64x640 bf16 hidden tile in LDS (tanh x1), XOR-swizzled.
// One barrier. Phase 2: 20 K-steps pure MFMA, B direct from L2 (frag-packed).
// NOTE: XOR swizzle MUST be applied to the complete byte address (it shares
// bit 6 with ks*64 — hoisting it out of the loop corrupts via carry).
// ---------------------------------------------------------------------------
__global__ __launch_bounds__(1024, 4) void k_main(const float* __restrict__ ED,
                                                  const u16* __restrict__ W2B,
                                                  const float* __restrict__ b2,
                                                  float* __restrict__ out) {
  __shared__ u16 At[BM * INNER];   // 81920 B, byte ^= (row&7)<<4
  char* At_b = reinterpret_cast<char*>(At);

  const int tid = threadIdx.x;
  const int m0 = blockIdx.x * BM;

  // ---- Phase 1: hidden tile, 5120 8-elem chunks over 1024 threads ----
#pragma unroll
  for (int i = 0; i < 5; ++i) {
    const int c = i * 1024 + tid;
    const int row = c / 80;
    const int kc = (c - row * 80) * 8;
    const int m = m0 + row;
    const int b = m / (T * U);
    const int rem = m - b * (T * U);
    const int t = rem / U;
    const int u = rem - t * U;
    const float* Erow = ED + (size_t)(b * T + t) * INNER + kc;
    const float* Drow = ED + (size_t)(ROWS_E + b * U + u) * INNER + kc;
    const float4 e0 = *reinterpret_cast<const float4*>(Erow);
    const float4 e1 = *reinterpret_cast<const float4*>(Erow + 4);
    const float4 d0 = *reinterpret_cast<const float4*>(Drow);
    const float4 d1 = *reinterpret_cast<const float4*>(Drow + 4);
    const u32 p0 = (u32)f2bf(fast_tanh(e0.x + d0.x)) |
                   ((u32)f2bf(fast_tanh(e0.y + d0.y)) << 16);
    const u32 p1 = (u32)f2bf(fast_tanh(e0.z + d0.z)) |
                   ((u32)f2bf(fast_tanh(e0.w + d0.w)) << 16);
    const u32 p2 = (u32)f2bf(fast_tanh(e1.x + d1.x)) |
                   ((u32)f2bf(fast_tanh(e1.y + d1.y)) << 16);
    const u32 p3 = (u32)f2bf(fast_tanh(e1.z + d1.z)) |
                   ((u32)f2bf(fast_tanh(e1.w + d1.w)) << 16);
    const int byte = (row * (INNER * 2) + kc * 2) ^ ((row & 7) << 4);
    int4 pk; pk.x = (int)p0; pk.y = (int)p1; pk.z = (int)p2; pk.w = (int)p3;
    *reinterpret_cast<int4*>(At_b + byte) = pk;
  }
  __syncthreads();   // the only barrier

  // ---- Phase 2: MFMA ----
  const int lane = tid & 63;
  const int w    = tid >> 6;     // 0..15, cols [w*64, w*64+64)
  const int llo  = lane & 15;
  const int lhi  = lane >> 4;

  // A addressing: row = mi*16 + llo; swizzle applied LAST each iteration.
  int abase[4];
  const int aswz = (llo & 7) << 4;           // (row&7)<<4 == (llo&7)<<4
#pragma unroll
  for (int mi = 0; mi < 4; ++mi)
    abase[mi] = (mi * 16 + llo) * (INNER * 2) + lhi * 16;

  // B base: fragment f = ks*64 + (w*4+ni); u16 offset = f*512 + lane*8
  const u16* Bp = W2B + ((size_t)(w * 4) * 512 + (size_t)lane * 8);

  f32x4 acc[4][4];
#pragma unroll
  for (int mi = 0; mi < 4; ++mi)
#pragma unroll
    for (int ni = 0; ni < 4; ++ni) acc[mi][ni] = (f32x4){0.f, 0.f, 0.f, 0.f};

#pragma unroll 2
  for (int ks = 0; ks < KST; ++ks) {
    bf16x8 a[4];
#pragma unroll
    for (int mi = 0; mi < 4; ++mi)
      a[mi] = *reinterpret_cast<const bf16x8*>(At_b + ((abase[mi] + ks * 64) ^ aswz));
    bf16x8 bfr[4];
#pragma unroll
    for (int ni = 0; ni < 4; ++ni)
      bfr[ni] = *reinterpret_cast<const bf16x8*>(Bp + (size_t)ks * 32768 + ni * 512);
#pragma unroll
    for (int mi = 0; mi < 4; ++mi)
#pragma unroll
      for (int ni = 0; ni < 4; ++ni)
        acc[mi][ni] = __builtin_amdgcn_mfma_f32_16x16x32_bf16(a[mi], bfr[ni], acc[mi][ni], 0, 0, 0);
  }

  // ---- Epilogue ----
  float b2v[4];
#pragma unroll
  for (int ni = 0; ni < 4; ++ni) b2v[ni] = b2[w * 64 + ni * 16 + llo];

#pragma unroll
  for (int mi = 0; mi < 4; ++mi) {
#pragma unroll
    for (int q = 0; q < 4; ++q) {
      const int row = m0 + mi * 16 + lhi * 4 + q;
      float* orow = out + (size_t)row * VOCAB + w * 64 + llo;
#pragma unroll
      for (int ni = 0; ni < 4; ++ni)
        orow[ni * 16] = acc[mi][ni][q] + b2v[ni];
    }
  }
}

}  // namespace

extern "C" void kernel_launch(void* const* d_in, const int* in_sizes, int n_in,
                              void* d_out, int out_size, void* d_ws, size_t ws_size,
                              hipStream_t stream) {
  const float* enc = (const float*)d_in[0];
  const float* dec = (const float*)d_in[1];
  const float* W1  = (const float*)d_in[2];
  const float* b1  = (const float*)d_in[3];
  const float* W2  = (const float*)d_in[4];
  const float* b2  = (const float*)d_in[5];
  float* out = (float*)d_out;

  float* ED  = (float*)d_ws;                                        // 5,120,000 B
  u16*   W2B = (u16*)((char*)d_ws + (size_t)ROWS_ED * INNER * 4);   // 1,310,720 B

  hipLaunchKernelGGL(k_prep, dim3(506), dim3(320), 0, stream,
                     enc, dec, W1, b1, W2, ED, W2B);
  hipLaunchKernelGGL(k_main, dim3(M_TOTAL / BM), dim3(1024), 0, stream,
                     ED, W2B, b2, out);
}